// Round 9
// baseline (368.836 us; speedup 1.0000x reference)
//
#include <hip/hip_runtime.h>
#include <hip/hip_cooperative_groups.h>
#include <cfloat>

namespace cg = cooperative_groups;

#define NN 1024

// ---- ws layout (bytes) ----
// 0x000000 dhp   float[1024*1024] sqrt(dh)  (4 MiB)
// 0x400000 dpp   float[1024*1024] sqrt(dp)  (4 MiB)
// 0x800000 XHT   float[64][1024]  (256 KiB)
// 0x840000 XPT   float[32][1024]  (128 KiB)
// 0x860000 eidx  int[1024][16]    (64 KiB)  NO init: 0xAA poison is negative
// 0x870000 bmax  float2[256]      (2 KiB)   per-block {max dh^2, max dp^2}, fully written
// 0x872000 cdeg  int[1024]        (init K in phase A, +indeg phase C, -overlap phase D)
// 0x874000 S1    double[32][64]   (16 KiB, zeroed in phase A)
// 0x878000 S2    double[32][64]   (16 KiB, zeroed in phase A)
// 0x880000 x     float[1024*64]   (256 KiB)
// 0x8C0000 y     float[1024*64]   (256 KiB)
// end 0x900000 (9 MiB)

__global__ __launch_bounds__(256, 1) void gcn_mega(
    const float* __restrict__ XH, const float* __restrict__ XP,
    const float* __restrict__ XX, const int* __restrict__ kptr,
    const float* __restrict__ W, const float* __restrict__ bias,
    const float* __restrict__ psi_w, const float* __restrict__ gamma,
    const float* __restrict__ beta,
    float* __restrict__ dhp, float* __restrict__ dpp,
    float* __restrict__ XHT, float* __restrict__ XPT,
    int* __restrict__ eidx, float2* __restrict__ bmax,
    int* __restrict__ cdeg, double* __restrict__ S1, double* __restrict__ S2,
    float* __restrict__ x, float* __restrict__ y,
    float* __restrict__ out)
{
    cg::grid_group grid = cg::this_grid();
    const int b = blockIdx.x;          // 256 blocks, 256 threads
    const int tid = threadIdx.x;
    const int w = tid >> 6, lane = tid & 63;

    __shared__ float th[64][65];
    __shared__ float tp[32][65];
    __shared__ float xybuf[4][2][64];
    __shared__ float shi[4][64];
    __shared__ float spi[4][32];
    __shared__ float wred[4][2];

    // ================= Phase A: transpose | x/y GEMM | init =================
    if (b < 16) {
        const int j0 = b * 64;
#pragma unroll
        for (int it = 0; it < 16; ++it) {
            int idx = it * 256 + tid;
            int jl = idx >> 6, d = idx & 63;
            th[d][jl] = XH[(j0 + jl) * 64 + d];
        }
#pragma unroll
        for (int it = 0; it < 8; ++it) {
            int idx = it * 256 + tid;
            int jl = idx >> 5, d = idx & 31;
            tp[d][jl] = XP[(j0 + jl) * 32 + d];
        }
        __syncthreads();
#pragma unroll
        for (int it = 0; it < 16; ++it) {
            int idx = it * 256 + tid;
            int d = idx >> 6, jl = idx & 63;
            XHT[d * NN + j0 + jl] = th[d][jl];
        }
#pragma unroll
        for (int it = 0; it < 8; ++it) {
            int idx = it * 256 + tid;
            int d = idx >> 6, jl = idx & 63;
            XPT[d * NN + j0 + jl] = tp[d][jl];
        }
    } else if (b < 80) {
        const int ibase = (b - 16) * 16 + w * 4;
#pragma unroll
        for (int r = 0; r < 4; ++r) {
            const int i = ibase + r;
            xybuf[w][0][lane] = XX[i * 64 + lane];
            __syncthreads();
            float acc = 0.f;
#pragma unroll
            for (int d = 0; d < 64; ++d) acc += xybuf[w][0][d] * W[d * 64 + lane];
            x[i * 64 + lane] = acc;
            xybuf[w][1][lane] = acc;
            __syncthreads();
            float acc2 = 0.f;
            const float* pw = psi_w + lane * 64;
#pragma unroll
            for (int d = 0; d < 64; ++d) acc2 += xybuf[w][1][d] * pw[d];
            y[i * 64 + lane] = acc2;
        }
    } else if (b == 80) {
        const int K = *kptr;
#pragma unroll
        for (int k = 0; k < 16; ++k) S1[tid * 16 + k] = 0.0;  // covers S1+S2 (contiguous 4096 doubles)
#pragma unroll
        for (int q = 0; q < 4; ++q) cdeg[q * 256 + tid] = K;
    }
    grid.sync();

    // ================= Phase B: dist (block b -> rows 4b..4b+3, loop 4 j-chunks) ============
    {
        const int i0 = b * 4;
        shi[w][lane] = XH[(i0 + w) * 64 + lane];
        if (tid < 128) spi[tid >> 5][tid & 31] = XP[(i0 + (tid >> 5)) * 32 + (tid & 31)];
        __syncthreads();
        float mh = 0.f, mp = 0.f;
#pragma unroll
        for (int jc = 0; jc < 4; ++jc) {
            const int j = jc * 256 + tid;
            float dh[4] = {0.f, 0.f, 0.f, 0.f}, dp[4] = {0.f, 0.f, 0.f, 0.f};
#pragma unroll 16
            for (int d = 0; d < 64; ++d) {
                float v = XHT[d * NN + j];
#pragma unroll
                for (int r = 0; r < 4; ++r) { float t = v - shi[r][d]; dh[r] += t * t; }
            }
#pragma unroll 16
            for (int d = 0; d < 32; ++d) {
                float v = XPT[d * NN + j];
#pragma unroll
                for (int r = 0; r < 4; ++r) { float t = v - spi[r][d]; dp[r] += t * t; }
            }
#pragma unroll
            for (int r = 0; r < 4; ++r) {
                dhp[(size_t)(i0 + r) * NN + j] = sqrtf(dh[r]);
                dpp[(size_t)(i0 + r) * NN + j] = sqrtf(dp[r]);
            }
            mh = fmaxf(mh, fmaxf(fmaxf(dh[0], dh[1]), fmaxf(dh[2], dh[3])));
            mp = fmaxf(mp, fmaxf(fmaxf(dp[0], dp[1]), fmaxf(dp[2], dp[3])));
        }
#pragma unroll
        for (int m = 1; m < 64; m <<= 1) {
            mh = fmaxf(mh, __shfl_xor(mh, m));
            mp = fmaxf(mp, __shfl_xor(mp, m));
        }
        if (lane == 0) { wred[w][0] = mh; wred[w][1] = mp; }
        __syncthreads();
        if (tid == 0) {
            float a = fmaxf(fmaxf(wred[0][0], wred[1][0]), fmaxf(wred[2][0], wred[3][0]));
            float b2 = fmaxf(fmaxf(wred[0][1], wred[1][1]), fmaxf(wred[2][1], wred[3][1]));
            bmax[b] = make_float2(a, b2);
        }
    }
    grid.sync();

    // ================= Phase C: top-K (wave -> row i = 4b + w) =================
    {
        // reduce 256 per-block maxes
        float2 v = bmax[tid];
        float mh = v.x, mp = v.y;
#pragma unroll
        for (int m = 1; m < 64; m <<= 1) {
            mh = fmaxf(mh, __shfl_xor(mh, m));
            mp = fmaxf(mp, __shfl_xor(mp, m));
        }
        __syncthreads();   // wred reuse hazard vs phase B
        if (lane == 0) { wred[w][0] = mh; wred[w][1] = mp; }
        __syncthreads();
        mh = fmaxf(fmaxf(wred[0][0], wred[1][0]), fmaxf(wred[2][0], wred[3][0]));
        mp = fmaxf(fmaxf(wred[0][1], wred[1][1]), fmaxf(wred[2][1], wred[3][1]));
        const float cH = -0.5f / sqrtf(mh);
        const float cP = -1.0f / sqrtf(mp);
        const int i = b * 4 + w;
        const float4* dh4 = (const float4*)(dhp + (size_t)i * NN);
        const float4* dp4 = (const float4*)(dpp + (size_t)i * NN);
        unsigned long long kk[16];
#pragma unroll
        for (int s = 0; s < 4; ++s) {    // j = s*256 + lane*4 + q
            float4 a = dh4[s * 64 + lane];
            float4 bb = dp4[s * 64 + lane];
            float w0 = __expf(a.x * cH) + 0.2f * __expf(bb.x * cP);
            float w1 = __expf(a.y * cH) + 0.2f * __expf(bb.y * cP);
            float w2 = __expf(a.z * cH) + 0.2f * __expf(bb.z * cP);
            float w3 = __expf(a.w * cH) + 0.2f * __expf(bb.w * cP);
            int jb = s * 256 + lane * 4;
            kk[s * 4 + 0] = ((unsigned long long)__float_as_uint(w0) << 32) | (unsigned)(1023 - (jb + 0));
            kk[s * 4 + 1] = ((unsigned long long)__float_as_uint(w1) << 32) | (unsigned)(1023 - (jb + 1));
            kk[s * 4 + 2] = ((unsigned long long)__float_as_uint(w2) << 32) | (unsigned)(1023 - (jb + 2));
            kk[s * 4 + 3] = ((unsigned long long)__float_as_uint(w3) << 32) | (unsigned)(1023 - (jb + 3));
        }
        const int K = *kptr;
        int jsave = 0;
        for (int t = 0; t < K; ++t) {
            unsigned long long bk = 0ull;
#pragma unroll
            for (int vv = 0; vv < 16; ++vv) bk = kk[vv] > bk ? kk[vv] : bk;
#pragma unroll
            for (int m = 1; m < 64; m <<= 1) {
                unsigned long long o = __shfl_xor(bk, m);
                bk = o > bk ? o : bk;
            }
            int j = 1023 - (int)(bk & 0x3FFull);
            if (lane == t) jsave = j;
            if (((j >> 2) & 63) == lane) {
                int slot = ((j >> 8) << 2) | (j & 3);
#pragma unroll
                for (int vv = 0; vv < 16; ++vv)
                    if (vv == slot) kk[vv] = 0ull;
            }
        }
        if (lane < K) {
            eidx[i * 16 + lane] = jsave;
            atomicAdd(&cdeg[jsave], 1);
        }
    }
    grid.sync();

    // ================= Phase D: overlap (blocks 0-63) =================
    if (b < 64) {
        const int gid = b * 256 + tid;
        const int i = gid >> 4;
        const int j = eidx[gid];
        if (j >= 0) {
            const int4* ej = (const int4*)(eidx + j * 16);
            bool rec = false;
#pragma unroll
            for (int q = 0; q < 4; ++q) {
                int4 e = ej[q];
                rec |= (e.x == i) | (e.y == i) | (e.z == i) | (e.w == i);
            }
            if (rec) atomicSub(&cdeg[j], 1);
        }
    }
    grid.sync();

    // ================= Phase E: BN raw moments (wave -> row j = 4b + w) =================
    {
        const int j = b * 4 + w;
        const int c = cdeg[j];
        const double yd = (double)y[j * 64 + lane];
        const int bin = (j & 31) * 64 + lane;
        atomicAdd(&S1[bin], (double)(NN + c) * yd);
        atomicAdd(&S2[bin], (double)(NN + 3 * c) * yd * yd);
    }
    grid.sync();

    // ================= Phase F: epilogue (wave -> row j = 4b + w) =================
    {
        const int j = b * 4 + w;
        double s1 = 0.0, s2 = 0.0;
#pragma unroll
        for (int q = 0; q < 32; ++q) { s1 += S1[q * 64 + lane]; s2 += S2[q * 64 + lane]; }
        const double m = s1 / 1048576.0;
        const double var = s2 / 1048576.0 - m * m;
        const float m0e = (float)m;
        const float scalee = (float)(1.0 / sqrt(var + 1e-5)) * gamma[lane];
        float t = y[j * 64 + lane];
        float z = (2.f * t - m0e) * scalee + beta[lane];
        float s = 1.f / (1.f + expf(-z));
        float val = x[j * 64 + lane] * ((float)(cdeg[j] - 1) * s + 1.f) + bias[lane];
        out[j * 64 + lane] = val;                  // output 0: out[:, :64]
        out[98304 + j * 64 + lane] = val;          // output 2: out
        if (lane < 32) out[65536 + j * 32 + lane] = XP[j * 32 + lane];  // output 1: XP
    }
}

extern "C" void kernel_launch(void* const* d_in, const int* in_sizes, int n_in,
                              void* d_out, int out_size, void* d_ws, size_t ws_size,
                              hipStream_t stream) {
    const float* XH    = (const float*)d_in[0];
    const float* XP    = (const float*)d_in[1];
    const float* XX    = (const float*)d_in[2];
    const int*   Kp    = (const int*)d_in[3];
    const float* W     = (const float*)d_in[4];
    const float* bias  = (const float*)d_in[5];
    const float* psi_w = (const float*)d_in[6];
    const float* psi_b = (const float*)d_in[7];
    const float* gamma = (const float*)d_in[8];
    const float* beta  = (const float*)d_in[9];
    (void)psi_b;  // cancels in (h - mu)
    float* out = (float*)d_out;
    char* ws = (char*)d_ws;

    float* dhp   = (float*)ws;
    float* dpp   = (float*)(ws + 0x400000);
    float* XHT   = (float*)(ws + 0x800000);
    float* XPT   = (float*)(ws + 0x840000);
    int* eidx    = (int*)(ws + 0x860000);
    float2* bmax = (float2*)(ws + 0x870000);
    int* cdeg    = (int*)(ws + 0x872000);
    double* S1   = (double*)(ws + 0x874000);
    double* S2   = (double*)(ws + 0x878000);
    float* x     = (float*)(ws + 0x880000);
    float* y     = (float*)(ws + 0x8C0000);

    void* args[] = {
        (void*)&XH, (void*)&XP, (void*)&XX, (void*)&Kp, (void*)&W, (void*)&bias,
        (void*)&psi_w, (void*)&gamma, (void*)&beta,
        (void*)&dhp, (void*)&dpp, (void*)&XHT, (void*)&XPT,
        (void*)&eidx, (void*)&bmax, (void*)&cdeg, (void*)&S1, (void*)&S2,
        (void*)&x, (void*)&y, (void*)&out
    };
    hipLaunchCooperativeKernel(reinterpret_cast<void*>(gcn_mega),
                               dim3(256), dim3(256), args, 0, stream);
}

// Round 11
// 144.093 us; speedup vs baseline: 2.5597x; 2.5597x over previous
//
#include <hip/hip_runtime.h>
#include <cfloat>

#define NN 1024

// ---- ws layout (bytes) ----
// 0x000000 dhp    float[1024*1024]  sqrt(dh)   (4 MiB)
// 0x400000 dpp    float[1024*1024]  sqrt(dp)   (4 MiB)
// 0x800000 XHT    float[64][1024]   (256 KiB)
// 0x840000 XPT    float[32][1024]   (128 KiB)
// 0x860000 eidx   int[1024][16]     (64 KiB)  NO init: 0xAA poison is negative
// 0x870000 maxbits unsigned[64]: [0]=max dh^2, [32]=max dp^2 (zeroed by transpose)
// 0x871000 cdeg   int[1024]         (init K by dist, +indeg by topk, -overlap)
// 0x872000 S1bins double[32][64]    (16 KiB, zeroed by transpose)
// 0x876000 S2bins double[32][64]    (16 KiB, zeroed by transpose)
// 0x87A000 m0     float[64]
// 0x87A200 scale  float[64]
// 0x880000 x      float[1024*64]    (256 KiB)
// 0x8C0000 y      float[1024*64]    (256 KiB)
// end 0x900000 (9 MiB)

__global__ __launch_bounds__(256) void gcn_transpose(const float* __restrict__ XH,
                                                     const float* __restrict__ XP,
                                                     float* __restrict__ XHT,
                                                     float* __restrict__ XPT,
                                                     unsigned* __restrict__ maxbits,
                                                     double* __restrict__ Sbins) {
    const int b = blockIdx.x;        // 16 blocks, 64 rows each
    const int j0 = b * 64;
    const int tid = threadIdx.x;
    // side init: stat bins (4096 doubles / 16 blocks = 256 each) + maxbits
    Sbins[b * 256 + tid] = 0.0;
    if (b == 0 && tid < 64) maxbits[tid] = 0u;
    __shared__ float th[64][65];
    __shared__ float tp[32][65];
#pragma unroll
    for (int it = 0; it < 16; ++it) {
        int idx = it * 256 + tid;
        int jl = idx >> 6, d = idx & 63;
        th[d][jl] = XH[(j0 + jl) * 64 + d];
    }
#pragma unroll
    for (int it = 0; it < 8; ++it) {
        int idx = it * 256 + tid;
        int jl = idx >> 5, d = idx & 31;
        tp[d][jl] = XP[(j0 + jl) * 32 + d];
    }
    __syncthreads();
#pragma unroll
    for (int it = 0; it < 16; ++it) {
        int idx = it * 256 + tid;
        int d = idx >> 6, jl = idx & 63;
        XHT[d * NN + j0 + jl] = th[d][jl];
    }
#pragma unroll
    for (int it = 0; it < 8; ++it) {
        int idx = it * 256 + tid;
        int d = idx >> 6, jl = idx & 63;
        XPT[d * NN + j0 + jl] = tp[d][jl];
    }
}

// 1024 blocks: block = (i-group of 4) x (j-chunk of 256).
__global__ __launch_bounds__(256) void gcn_dist(const float* __restrict__ XH,
                                                const float* __restrict__ XP,
                                                const float* __restrict__ XHT,
                                                const float* __restrict__ XPT,
                                                float* __restrict__ dhp,
                                                float* __restrict__ dpp,
                                                unsigned* __restrict__ maxbits,
                                                const int* __restrict__ kptr,
                                                int* __restrict__ cdeg) {
    const int b = blockIdx.x;
    const int i0 = (b >> 2) * 4;
    const int j = (b & 3) * 256 + threadIdx.x;
    const int tid = threadIdx.x;
    if (b < 4) cdeg[j] = *kptr;      // covers j=0..1023 exactly once
    __shared__ float shi[4][64];
    __shared__ float spi[4][32];
    shi[tid >> 6][tid & 63] = XH[(i0 + (tid >> 6)) * 64 + (tid & 63)];
    if (tid < 128) spi[tid >> 5][tid & 31] = XP[(i0 + (tid >> 5)) * 32 + (tid & 31)];
    __syncthreads();
    float dh[4] = {0.f, 0.f, 0.f, 0.f}, dp[4] = {0.f, 0.f, 0.f, 0.f};
#pragma unroll 16
    for (int d = 0; d < 64; ++d) {
        float v = XHT[d * NN + j];
#pragma unroll
        for (int r = 0; r < 4; ++r) { float t = v - shi[r][d]; dh[r] += t * t; }
    }
#pragma unroll 16
    for (int d = 0; d < 32; ++d) {
        float v = XPT[d * NN + j];
#pragma unroll
        for (int r = 0; r < 4; ++r) { float t = v - spi[r][d]; dp[r] += t * t; }
    }
#pragma unroll
    for (int r = 0; r < 4; ++r) {
        dhp[(size_t)(i0 + r) * NN + j] = sqrtf(dh[r]);
        dpp[(size_t)(i0 + r) * NN + j] = sqrtf(dp[r]);
    }
    float mh = fmaxf(fmaxf(dh[0], dh[1]), fmaxf(dh[2], dh[3]));
    float mp = fmaxf(fmaxf(dp[0], dp[1]), fmaxf(dp[2], dp[3]));
#pragma unroll
    for (int m = 1; m < 64; m <<= 1) {
        mh = fmaxf(mh, __shfl_xor(mh, m));
        mp = fmaxf(mp, __shfl_xor(mp, m));
    }
    __shared__ float wmx[4][2];
    if ((tid & 63) == 0) { wmx[tid >> 6][0] = mh; wmx[tid >> 6][1] = mp; }
    __syncthreads();
    if (tid == 0) {
        float a = fmaxf(fmaxf(wmx[0][0], wmx[1][0]), fmaxf(wmx[2][0], wmx[3][0]));
        float b2 = fmaxf(fmaxf(wmx[0][1], wmx[1][1]), fmaxf(wmx[2][1], wmx[3][1]));
        atomicMax(&maxbits[0], __float_as_uint(a));
        atomicMax(&maxbits[32], __float_as_uint(b2));
    }
}

// 256 blocks x 4 waves; wave owns row i. Exact u64-packed top-K selection.
__global__ __launch_bounds__(256) void gcn_topk(const float* __restrict__ dhp,
                                                const float* __restrict__ dpp,
                                                const unsigned* __restrict__ maxbits,
                                                const int* __restrict__ kptr,
                                                int* __restrict__ eidx,
                                                int* __restrict__ cdeg) {
    const int tid = threadIdx.x;
    const int w = tid >> 6, lane = tid & 63;
    const int i = blockIdx.x * 4 + w;
    const float cH = -0.5f / sqrtf(__uint_as_float(maxbits[0]));
    const float cP = -1.0f / sqrtf(__uint_as_float(maxbits[32]));
    const float4* dh4 = (const float4*)(dhp + (size_t)i * NN);
    const float4* dp4 = (const float4*)(dpp + (size_t)i * NN);
    unsigned long long kk[16];
#pragma unroll
    for (int s = 0; s < 4; ++s) {    // j = s*256 + lane*4 + q
        float4 a = dh4[s * 64 + lane];
        float4 b = dp4[s * 64 + lane];
        float w0 = __expf(a.x * cH) + 0.2f * __expf(b.x * cP);
        float w1 = __expf(a.y * cH) + 0.2f * __expf(b.y * cP);
        float w2 = __expf(a.z * cH) + 0.2f * __expf(b.z * cP);
        float w3 = __expf(a.w * cH) + 0.2f * __expf(b.w * cP);
        int jb = s * 256 + lane * 4;
        kk[s * 4 + 0] = ((unsigned long long)__float_as_uint(w0) << 32) | (unsigned)(1023 - (jb + 0));
        kk[s * 4 + 1] = ((unsigned long long)__float_as_uint(w1) << 32) | (unsigned)(1023 - (jb + 1));
        kk[s * 4 + 2] = ((unsigned long long)__float_as_uint(w2) << 32) | (unsigned)(1023 - (jb + 2));
        kk[s * 4 + 3] = ((unsigned long long)__float_as_uint(w3) << 32) | (unsigned)(1023 - (jb + 3));
    }
    const int K = *kptr;
    int jsave = 0;
    for (int t = 0; t < K; ++t) {
        unsigned long long bk = 0ull;
#pragma unroll
        for (int v = 0; v < 16; ++v) bk = kk[v] > bk ? kk[v] : bk;
#pragma unroll
        for (int m = 1; m < 64; m <<= 1) {
            unsigned long long o = __shfl_xor(bk, m);
            bk = o > bk ? o : bk;
        }
        int j = 1023 - (int)(bk & 0x3FFull);
        if (lane == t) jsave = j;
        if (((j >> 2) & 63) == lane) {
            int slot = ((j >> 8) << 2) | (j & 3);
#pragma unroll
            for (int v = 0; v < 16; ++v)
                if (v == slot) kk[v] = 0ull;
        }
    }
    if (lane < K) {
        eidx[i * 16 + lane] = jsave;
        atomicAdd(&cdeg[jsave], 1);
    }
}

// 16K threads: edge t of row i -> j; cdeg[j] -= (i in eidx[j]). Stale slots negative.
__global__ __launch_bounds__(256) void gcn_overlap(const int* __restrict__ eidx,
                                                   int* __restrict__ cdeg) {
    const int gid = blockIdx.x * 256 + threadIdx.x;
    const int i = gid >> 4;
    const int j = eidx[gid];
    if (j < 0) return;
    const int4* ej = (const int4*)(eidx + j * 16);
    bool rec = false;
#pragma unroll
    for (int q = 0; q < 4; ++q) {
        int4 e = ej[q];
        rec |= (e.x == i) | (e.y == i) | (e.z == i) | (e.w == i);
    }
    if (rec) atomicSub(&cdeg[j], 1);
}

// x = XX@W, y = x@psi_w^T; fused BN raw-moment accumulation (32 bins, f64 atomics).
__global__ __launch_bounds__(64) void gcn_xy(const float* __restrict__ XX,
                                             const float* __restrict__ W,
                                             const float* __restrict__ psi_w,
                                             const int* __restrict__ cdeg,
                                             float* __restrict__ x,
                                             float* __restrict__ y,
                                             double* __restrict__ S1,
                                             double* __restrict__ S2) {
    const int i = blockIdx.x;
    const int e = threadIdx.x;  // 64
    __shared__ float xin[64], xs[64];
    xin[e] = XX[i * 64 + e];
    __syncthreads();
    float acc = 0.f;
#pragma unroll
    for (int d = 0; d < 64; ++d) acc += xin[d] * W[d * 64 + e];
    xs[e] = acc;
    x[i * 64 + e] = acc;
    __syncthreads();
    float acc2 = 0.f;
    const float* pw = psi_w + e * 64;
#pragma unroll
    for (int d = 0; d < 64; ++d) acc2 += xs[d] * pw[d];
    y[i * 64 + e] = acc2;
    const int c = cdeg[i];
    const int bin = (i & 31) * 64 + e;
    double yd = (double)acc2;
    atomicAdd(&S1[bin], (double)(NN + c) * yd);
    atomicAdd(&S2[bin], (double)(NN + 3 * c) * yd * yd);
}

__global__ __launch_bounds__(64) void gcn_statsfin(const double* __restrict__ S1,
                                                   const double* __restrict__ S2,
                                                   const float* __restrict__ gamma,
                                                   float* __restrict__ m0,
                                                   float* __restrict__ scale) {
    const int e = threadIdx.x;  // 1 block x 64
    double s1 = 0.0, s2 = 0.0;
#pragma unroll
    for (int b = 0; b < 32; ++b) { s1 += S1[b * 64 + e]; s2 += S2[b * 64 + e]; }
    double m = s1 / 1048576.0;
    double var = s2 / 1048576.0 - m * m;
    m0[e] = (float)m;
    scale[e] = (float)(1.0 / sqrt(var + 1e-5)) * gamma[e];
}

__global__ __launch_bounds__(64) void gcn_out(const float* __restrict__ x,
                                              const float* __restrict__ y,
                                              const int* __restrict__ cdeg,
                                              const float* __restrict__ beta,
                                              const float* __restrict__ m0,
                                              const float* __restrict__ scale,
                                              const float* __restrict__ bias,
                                              const float* __restrict__ XP,
                                              float* __restrict__ out) {
    const int j = blockIdx.x;
    const int e = threadIdx.x;  // 64
    float t = y[j * 64 + e];
    float z = (2.f * t - m0[e]) * scale[e] + beta[e];
    float s = 1.f / (1.f + expf(-z));
    float val = x[j * 64 + e] * ((float)(cdeg[j] - 1) * s + 1.f) + bias[e];
    out[j * 64 + e] = val;                  // output 0: out[:, :64]
    out[98304 + j * 64 + e] = val;          // output 2: out
    if (e < 32) out[65536 + j * 32 + e] = XP[j * 32 + e];  // output 1: XP
}

extern "C" void kernel_launch(void* const* d_in, const int* in_sizes, int n_in,
                              void* d_out, int out_size, void* d_ws, size_t ws_size,
                              hipStream_t stream) {
    const float* XH    = (const float*)d_in[0];
    const float* XP    = (const float*)d_in[1];
    const float* XX    = (const float*)d_in[2];
    const int*   Kp    = (const int*)d_in[3];
    const float* W     = (const float*)d_in[4];
    const float* bias  = (const float*)d_in[5];
    const float* psi_w = (const float*)d_in[6];
    const float* psi_b = (const float*)d_in[7];
    const float* gamma = (const float*)d_in[8];
    const float* beta  = (const float*)d_in[9];
    (void)psi_b;  // cancels in (h - mu)
    float* out = (float*)d_out;
    char* ws = (char*)d_ws;

    float* dhp        = (float*)ws;
    float* dpp        = (float*)(ws + 0x400000);
    float* XHT        = (float*)(ws + 0x800000);
    float* XPT        = (float*)(ws + 0x840000);
    int* eidx         = (int*)(ws + 0x860000);
    unsigned* maxbits = (unsigned*)(ws + 0x870000);
    int* cdeg         = (int*)(ws + 0x871000);
    double* S1        = (double*)(ws + 0x872000);
    double* S2        = (double*)(ws + 0x876000);
    float* m0         = (float*)(ws + 0x87A000);
    float* scale      = (float*)(ws + 0x87A200);
    float* x          = (float*)(ws + 0x880000);
    float* y          = (float*)(ws + 0x8C0000);

    gcn_transpose<<<dim3(16), dim3(256), 0, stream>>>(XH, XP, XHT, XPT, maxbits, S1);
    gcn_dist<<<dim3(1024), dim3(256), 0, stream>>>(XH, XP, XHT, XPT, dhp, dpp, maxbits, Kp, cdeg);
    gcn_topk<<<dim3(256), dim3(256), 0, stream>>>(dhp, dpp, maxbits, Kp, eidx, cdeg);
    gcn_overlap<<<dim3(64), dim3(256), 0, stream>>>(eidx, cdeg);
    gcn_xy<<<dim3(1024), dim3(64), 0, stream>>>(XX, W, psi_w, cdeg, x, y, S1, S2);
    gcn_statsfin<<<dim3(1), dim3(64), 0, stream>>>(S1, S2, gamma, m0, scale);
    gcn_out<<<dim3(1024), dim3(64), 0, stream>>>(x, y, cdeg, beta, m0, scale, bias, XP, out);
}